// Round 2
// baseline (1012.229 us; speedup 1.0000x reference)
//
#include <hip/hip_runtime.h>
#include <cstdint>
#include <cstddef>

#define T_TOK 4096
#define D_DIM 1024
#define F_DIM 768
#define E_NUM 64
#define LDT   72   // BK(=64) + 8 bf16 pad: breaks power-of-2 LDS stride

typedef __bf16 bf16;
typedef __bf16 bf16x4 __attribute__((ext_vector_type(4)));
typedef __bf16 bf16x8 __attribute__((ext_vector_type(8)));
typedef float  f32x4  __attribute__((ext_vector_type(4)));

// ---------------- gating: fp32 logits, top-8, renormalized weights ----------
__global__ __launch_bounds__(256) void gating_kernel(
    const float* __restrict__ x, const float* __restrict__ gw,
    int* __restrict__ topk_ids, float* __restrict__ topk_w, int* __restrict__ counts)
{
  __shared__ float xs[64][33];
  __shared__ float gs[64][33];
  __shared__ float lg[64][65];
  __shared__ int   lcnt[64];
  const int tid = threadIdx.x;
  const int t0  = blockIdx.x * 64;
  const int e   = tid & 63, tg = tid >> 6;
  float acc[16];
#pragma unroll
  for (int i = 0; i < 16; ++i) acc[i] = 0.f;
  for (int k0 = 0; k0 < D_DIM; k0 += 32) {
    __syncthreads();
#pragma unroll
    for (int it = 0; it < 2; ++it) {
      int slot = tid + it * 256;
      int r = slot >> 3, c = (slot & 7) * 4;
      float4 xv = *(const float4*)(x + (size_t)(t0 + r) * D_DIM + k0 + c);
      xs[r][c] = xv.x; xs[r][c+1] = xv.y; xs[r][c+2] = xv.z; xs[r][c+3] = xv.w;
      float4 gv = *(const float4*)(gw + (size_t)r * D_DIM + k0 + c);
      gs[r][c] = gv.x; gs[r][c+1] = gv.y; gs[r][c+2] = gv.z; gs[r][c+3] = gv.w;
    }
    __syncthreads();
#pragma unroll
    for (int kk = 0; kk < 32; ++kk) {
      float g = gs[e][kk];
#pragma unroll
      for (int tt = 0; tt < 16; ++tt) acc[tt] += g * xs[tg * 16 + tt][kk];
    }
  }
  __syncthreads();
#pragma unroll
  for (int tt = 0; tt < 16; ++tt) lg[tg * 16 + tt][e] = acc[tt];
  if (tid < 64) lcnt[tid] = 0;
  __syncthreads();
  if (tid < 64) {
    const int t = t0 + tid;
    float sv[8]; int se[8];
#pragma unroll
    for (int i = 0; i < 8; ++i) {
      float best = -3.4e38f; int be = 0;
      for (int j = 0; j < 64; ++j) {
        float v = lg[tid][j];
        if (v > best) { best = v; be = j; }   // strict > : ties pick lowest idx (matches top_k)
      }
      sv[i] = best; se[i] = be;
      lg[tid][be] = -3.4e38f;
    }
    // softmax denominator cancels under renormalization over the top-8
    float m0 = sv[0], s = 0.f, w[8];
#pragma unroll
    for (int i = 0; i < 8; ++i) { w[i] = __expf(sv[i] - m0); s += w[i]; }
    float inv = 1.f / s;
#pragma unroll
    for (int i = 0; i < 8; ++i) {
      topk_w[t * 8 + i]   = w[i] * inv;
      topk_ids[t * 8 + i] = se[i];
      atomicAdd(&lcnt[se[i]], 1);
    }
  }
  __syncthreads();
  if (tid < 64) atomicAdd(&counts[tid], lcnt[tid]);
}

// ---------------- x fp32 -> bf16 ----------------
__global__ __launch_bounds__(256) void cast_x_kernel(const float* __restrict__ x, bf16* __restrict__ xb)
{
  int i = blockIdx.x * 256 + threadIdx.x;     // exactly T*D/8 threads
  const float4* p = (const float4*)x + (size_t)i * 2;
  float4 a = p[0], b = p[1];
  bf16x8 v;
  v[0]=(bf16)a.x; v[1]=(bf16)a.y; v[2]=(bf16)a.z; v[3]=(bf16)a.w;
  v[4]=(bf16)b.x; v[5]=(bf16)b.y; v[6]=(bf16)b.z; v[7]=(bf16)b.w;
  *(bf16x8*)(xb + (size_t)i * 8) = v;
}

// ---------------- plan: offsets + 128-row m-tile table ----------------
__global__ void plan_kernel(const int* __restrict__ counts, int* __restrict__ offsets,
                            int* __restrict__ tile_e, int* __restrict__ tile_m0,
                            int* __restrict__ ntiles)
{
  if (threadIdx.x == 0) {
    int off = 0, nt = 0;
    for (int e = 0; e < E_NUM; ++e) {
      offsets[e] = off;
      int c = counts[e];
      int m = (c + 127) >> 7;
      for (int i = 0; i < m; ++i) { tile_e[nt] = e; tile_m0[nt] = i << 7; ++nt; }
      off += c;
    }
    ntiles[0] = nt;
  }
}

// ---------------- scatter expanded tokens into expert buckets ----------------
__global__ __launch_bounds__(256) void scatter_kernel(
    const int* __restrict__ ids, const float* __restrict__ w,
    const int* __restrict__ offsets, int* __restrict__ fill,
    int* __restrict__ row_token, float* __restrict__ row_weight)
{
  int i = blockIdx.x * 256 + threadIdx.x;     // < 32768
  int e = ids[i];
  int pos = offsets[e] + atomicAdd(&fill[e], 1);
  row_token[pos]  = i >> 3;
  row_weight[pos] = w[i];
}

// ---------------- GEMM1: h = silu(x W_g^T) * (x W_u^T), bf16 out ------------
__global__ __launch_bounds__(256) void gemm1_kernel(
    const bf16* __restrict__ xb, const float* __restrict__ w_gate, const float* __restrict__ w_up,
    const int* __restrict__ tile_e, const int* __restrict__ tile_m0, const int* __restrict__ ntiles,
    const int* __restrict__ offsets, const int* __restrict__ counts,
    const int* __restrict__ row_token, bf16* __restrict__ h)
{
  __shared__ bf16 As[128 * LDT];
  __shared__ bf16 Bg[64 * LDT];
  __shared__ bf16 Bu[64 * LDT];
  const int tid = threadIdx.x;
  const int wave = tid >> 6, lane = tid & 63;
  const int q = lane >> 4, lm = lane & 15;
  const int n_jobs = ntiles[0] * 12;          // 12 n-tiles of 64 over F=768
  for (int job = blockIdx.x; job < n_jobs; job += gridDim.x) {
    const int mt = job / 12, nt = job - mt * 12;   // mt-major: expert locality in time
    const int e = tile_e[mt], m0 = tile_m0[mt];
    const int base = offsets[e], cnt = counts[e];
    const int n0 = nt * 64;
    const float* wg = w_gate + (size_t)e * (F_DIM * D_DIM) + (size_t)n0 * D_DIM;
    const float* wu = w_up   + (size_t)e * (F_DIM * D_DIM) + (size_t)n0 * D_DIM;
    const bf16* aptr[4];
#pragma unroll
    for (int it = 0; it < 4; ++it) {
      int slot = tid + it * 256;
      int r = slot >> 3;
      int row = m0 + r;
      int tok = row_token[base + ((row < cnt) ? row : 0)];  // clamp: garbage rows never stored
      aptr[it] = xb + (size_t)tok * D_DIM + ((slot & 7) * 8);
    }
    f32x4 zero = {0.f, 0.f, 0.f, 0.f};
    f32x4 accg[2][4], accu[2][4];
#pragma unroll
    for (int mi = 0; mi < 2; ++mi)
#pragma unroll
      for (int ni = 0; ni < 4; ++ni) { accg[mi][ni] = zero; accu[mi][ni] = zero; }
    for (int k0 = 0; k0 < D_DIM; k0 += 64) {
      __syncthreads();
#pragma unroll
      for (int it = 0; it < 4; ++it) {
        int slot = tid + it * 256;
        int r = slot >> 3, c = (slot & 7) * 8;
        *(uint4*)(&As[r * LDT + c]) = *(const uint4*)(aptr[it] + k0);
      }
#pragma unroll
      for (int it = 0; it < 4; ++it) {
        int slot = tid + it * 256;
        int r = slot >> 4, c = (slot & 15) * 4;
        float4 g = *(const float4*)(wg + (size_t)r * D_DIM + k0 + c);
        float4 u = *(const float4*)(wu + (size_t)r * D_DIM + k0 + c);
        bf16x4 gb; gb[0]=(bf16)g.x; gb[1]=(bf16)g.y; gb[2]=(bf16)g.z; gb[3]=(bf16)g.w;
        bf16x4 ub; ub[0]=(bf16)u.x; ub[1]=(bf16)u.y; ub[2]=(bf16)u.z; ub[3]=(bf16)u.w;
        *(bf16x4*)(&Bg[r * LDT + c]) = gb;
        *(bf16x4*)(&Bu[r * LDT + c]) = ub;
      }
      __syncthreads();
#pragma unroll
      for (int ks = 0; ks < 2; ++ks) {
        const int kk = ks * 32 + q * 8;
        bf16x8 a0 = *(const bf16x8*)(&As[(wave * 32 + lm) * LDT + kk]);
        bf16x8 a1 = *(const bf16x8*)(&As[(wave * 32 + 16 + lm) * LDT + kk]);
#pragma unroll
        for (int ni = 0; ni < 4; ++ni) {
          bf16x8 bg = *(const bf16x8*)(&Bg[(ni * 16 + lm) * LDT + kk]);
          bf16x8 bu = *(const bf16x8*)(&Bu[(ni * 16 + lm) * LDT + kk]);
          accg[0][ni] = __builtin_amdgcn_mfma_f32_16x16x32_bf16(a0, bg, accg[0][ni], 0, 0, 0);
          accg[1][ni] = __builtin_amdgcn_mfma_f32_16x16x32_bf16(a1, bg, accg[1][ni], 0, 0, 0);
          accu[0][ni] = __builtin_amdgcn_mfma_f32_16x16x32_bf16(a0, bu, accu[0][ni], 0, 0, 0);
          accu[1][ni] = __builtin_amdgcn_mfma_f32_16x16x32_bf16(a1, bu, accu[1][ni], 0, 0, 0);
        }
      }
    }
    // epilogue: C/D layout col=lane&15, row=(lane>>4)*4+reg
#pragma unroll
    for (int mi = 0; mi < 2; ++mi)
#pragma unroll
      for (int rr = 0; rr < 4; ++rr) {
        int row = wave * 32 + mi * 16 + q * 4 + rr;
        if (m0 + row < cnt) {
          bf16* hp = h + (size_t)(base + m0 + row) * F_DIM + n0 + lm;
#pragma unroll
          for (int ni = 0; ni < 4; ++ni) {
            float g = accg[mi][ni][rr], u = accu[mi][ni][rr];
            float sg = g / (1.f + __expf(-g));
            hp[ni * 16] = (bf16)(sg * u);
          }
        }
      }
  }
}

// ---------------- GEMM2: y += w * (h W_d^T), fp32 atomic accumulate to d_out -
__global__ __launch_bounds__(256) void gemm2_kernel(
    const bf16* __restrict__ h, const float* __restrict__ w_down,
    const int* __restrict__ tile_e, const int* __restrict__ tile_m0, const int* __restrict__ ntiles,
    const int* __restrict__ offsets, const int* __restrict__ counts,
    const int* __restrict__ row_token, const float* __restrict__ row_weight,
    float* __restrict__ y)
{
  __shared__ bf16 As[128 * LDT];
  __shared__ bf16 Bd[64 * LDT];
  const int tid = threadIdx.x;
  const int wave = tid >> 6, lane = tid & 63;
  const int q = lane >> 4, lm = lane & 15;
  const int n_jobs = ntiles[0] * 16;          // 16 n-tiles of 64 over D=1024
  for (int job = blockIdx.x; job < n_jobs; job += gridDim.x) {
    const int mt = job >> 4, nt = job & 15;
    const int e = tile_e[mt], m0 = tile_m0[mt];
    const int base = offsets[e], cnt = counts[e];
    const int n0 = nt * 64;
    const float* wd = w_down + (size_t)e * (D_DIM * F_DIM) + (size_t)n0 * F_DIM;
    const bf16* aptr[4];
#pragma unroll
    for (int it = 0; it < 4; ++it) {
      int slot = tid + it * 256;
      int r = slot >> 3;
      int row = m0 + r; if (row >= cnt) row = cnt - 1;   // clamp inside valid h rows
      aptr[it] = h + (size_t)(base + row) * F_DIM + ((slot & 7) * 8);
    }
    f32x4 zero = {0.f, 0.f, 0.f, 0.f};
    f32x4 acc[2][4];
#pragma unroll
    for (int mi = 0; mi < 2; ++mi)
#pragma unroll
      for (int ni = 0; ni < 4; ++ni) acc[mi][ni] = zero;
    for (int k0 = 0; k0 < F_DIM; k0 += 64) {
      __syncthreads();
#pragma unroll
      for (int it = 0; it < 4; ++it) {
        int slot = tid + it * 256;
        int r = slot >> 3, c = (slot & 7) * 8;
        *(uint4*)(&As[r * LDT + c]) = *(const uint4*)(aptr[it] + k0);
      }
#pragma unroll
      for (int it = 0; it < 4; ++it) {
        int slot = tid + it * 256;
        int r = slot >> 4, c = (slot & 15) * 4;
        float4 d = *(const float4*)(wd + (size_t)r * F_DIM + k0 + c);
        bf16x4 db; db[0]=(bf16)d.x; db[1]=(bf16)d.y; db[2]=(bf16)d.z; db[3]=(bf16)d.w;
        *(bf16x4*)(&Bd[r * LDT + c]) = db;
      }
      __syncthreads();
#pragma unroll
      for (int ks = 0; ks < 2; ++ks) {
        const int kk = ks * 32 + q * 8;
        bf16x8 a0 = *(const bf16x8*)(&As[(wave * 32 + lm) * LDT + kk]);
        bf16x8 a1 = *(const bf16x8*)(&As[(wave * 32 + 16 + lm) * LDT + kk]);
#pragma unroll
        for (int ni = 0; ni < 4; ++ni) {
          bf16x8 b = *(const bf16x8*)(&Bd[(ni * 16 + lm) * LDT + kk]);
          acc[0][ni] = __builtin_amdgcn_mfma_f32_16x16x32_bf16(a0, b, acc[0][ni], 0, 0, 0);
          acc[1][ni] = __builtin_amdgcn_mfma_f32_16x16x32_bf16(a1, b, acc[1][ni], 0, 0, 0);
        }
      }
    }
#pragma unroll
    for (int mi = 0; mi < 2; ++mi)
#pragma unroll
      for (int rr = 0; rr < 4; ++rr) {
        int row = wave * 32 + mi * 16 + q * 4 + rr;
        if (m0 + row < cnt) {
          int gr = base + m0 + row;
          int tok = row_token[gr];
          float wt = row_weight[gr];
          float* op = y + (size_t)tok * D_DIM + n0 + lm;
#pragma unroll
          for (int ni = 0; ni < 4; ++ni)
            atomicAdd(op + ni * 16, wt * acc[mi][ni][rr]);
        }
      }
  }
}

extern "C" void kernel_launch(void* const* d_in, const int* in_sizes, int n_in,
                              void* d_out, int out_size, void* d_ws, size_t ws_size,
                              hipStream_t stream)
{
  const float* x      = (const float*)d_in[0];
  const float* gate_w = (const float*)d_in[1];
  const float* w_gate = (const float*)d_in[2];
  const float* w_up   = (const float*)d_in[3];
  const float* w_down = (const float*)d_in[4];
  float* out = (float*)d_out;                 // reference output dtype is fp32
  char* ws = (char*)d_ws;
  // workspace layout (bytes)
  bf16*  xb        = (bf16*) (ws + 0);          // 4096*1024*2        = 8388608
  int*   topk_ids  = (int*)  (ws + 8388608);    // 32768*4            = 131072
  float* topk_wp   = (float*)(ws + 8519680);    // 131072
  int*   counts    = (int*)  (ws + 8650752);    // 256
  int*   fill      = (int*)  (ws + 8651008);    // 256
  int*   offsets   = (int*)  (ws + 8651264);    // 256
  int*   tile_e    = (int*)  (ws + 8651520);    // 1536
  int*   tile_m0   = (int*)  (ws + 8653056);    // 1536
  int*   ntiles    = (int*)  (ws + 8654592);    // 256
  int*   row_token = (int*)  (ws + 8654848);    // 131072
  float* row_wt    = (float*)(ws + 8785920);    // 131072
  bf16*  h         = (bf16*) (ws + 8916992);    // 32768*768*2        = 50331648
  // total = 59248640 bytes

  hipMemsetAsync(counts, 0, 512, stream);                 // counts + fill
  hipMemsetAsync(out, 0, (size_t)T_TOK * D_DIM * 4, stream);  // atomic accumulate base
  gating_kernel <<<T_TOK / 64, 256, 0, stream>>>(x, gate_w, topk_ids, topk_wp, counts);
  cast_x_kernel <<<(T_TOK * D_DIM) / (256 * 8), 256, 0, stream>>>(x, xb);
  plan_kernel   <<<1, 64, 0, stream>>>(counts, offsets, tile_e, tile_m0, ntiles);
  scatter_kernel<<<(T_TOK * 8) / 256, 256, 0, stream>>>(topk_ids, topk_wp, offsets, fill, row_token, row_wt);
  gemm1_kernel  <<<1024, 256, 0, stream>>>(xb, w_gate, w_up, tile_e, tile_m0, ntiles, offsets, counts, row_token, h);
  gemm2_kernel  <<<1024, 256, 0, stream>>>(h, w_down, tile_e, tile_m0, ntiles, offsets, counts, row_token, row_wt, out);
}